// Round 9
// baseline (82.720 us; speedup 1.0000x reference)
//
#include <hip/hip_runtime.h>
#include <math.h>

// Gaussians covariance, MI355X. cov = s^2 * I exactly (isotropic scales,
// R orthogonal) -> problem is the exact 3-NN search over N^2 pairs.
//
// R20 (ABLATION ROUND; R19 probe: gap/launch = 1.55us):
//  - Ledger (measured): fill 40.2 | resets ~13.7 | cellmin 7.8 | finalize
//    ~2.0 | 2 gaps 3.1. cellmin is 2x over its pipe model (~4); ablate
//    before optimizing (the fills hide per-kernel counters, so the
//    instrument is launch arithmetic on shadow variants).
//  - Launches: cellmin<FULL>(real) + finalize (output correct), then
//    cellmin<FULL>(shadow) [T1 calib: gap+T1 = 9.36 from R18, same krnl]
//    + cellmin<NOCOMPUTE>(shadow) [ds_reads kept via asm keepalive;
//    MFMA+min stream removed].
//    compute_core = 18.72 + base(~66.3) - dur.
//      dur >= 83.5 -> core <= 1.5us -> attack LDS/phases/barriers in R21
//      dur <= 82   -> core >= 3us   -> min stream not fusing; force min3
//  - R21 drops both shadows (banked ~-16us).
//  - Real kernels byte-identical to R19's (passed).
// NOTE: ~54us of the window is harness-fixed (fill + reset dispatches).

#define N_PTS 12288
#define CHUNK 768               // j's per chunk
#define NCH   (N_PTS / CHUNK)   // 16 chunks
#define CELLJ 24                // consecutive j's per cell; 32 cells/chunk
#define IBLK  256               // i's per pass-A block
#define NIB   (N_PTS / IBLK)    // 48
#define TSTR  260               // LDS transpose stride (dwords), 16B-aligned
#define CMASK 1023u             // 10-bit cell id (512 cells used)

typedef _Float16 half8  __attribute__((ext_vector_type(8)));
typedef float    f32x16 __attribute__((ext_vector_type(16)));

__device__ __forceinline__ void ins4(float d, float& a0, float& a1,
                                     float& a2, float& a3) {
    // insert d into sorted a0<=a1<=a2<=a3, keep 4 smallest (4 VALU)
    const float n0 = fminf(a0, d);
    const float n1 = __builtin_amdgcn_fmed3f(a0, a1, d);
    const float n2 = __builtin_amdgcn_fmed3f(a1, a2, d);
    const float n3 = __builtin_amdgcn_fmed3f(a2, a3, d);
    a0 = n0; a1 = n1; a2 = n2; a3 = n3;
}

// MODE 0 = full; MODE 1 = b-loop ds_reads kept (asm keepalive), no MFMA/min
template <int MODE>
__global__ __launch_bounds__(256, 3) void cellmin_k(
    const float* __restrict__ pts, float4* __restrict__ ws4)
{
    // union: sB (24 b-iters x 64 lane-slots x 8 halves = 24KB) during MFMA,
    // then sT (32 cells x 256 i, stride TSTR = 33.3KB) for the transpose
    __shared__ __align__(16) unsigned char shmem[32 * TSTR * 4];
    _Float16* sB = (_Float16*)shmem;
    float*    sT = (float*)shmem;

    const int t    = threadIdx.x;
    const int iblk = blockIdx.x * IBLK;
    const int g    = blockIdx.y;           // chunk 0..15

    // ---- stage B fragments: COALESCED (consecutive t -> consecutive j) ----
    #pragma unroll
    for (int it = 0; it < 3; ++it) {
        const int idx = t + it * 256;
        const int col = idx / CELLJ, b = idx % CELLJ;
        const int j = g * CHUNK + idx;       // == g*768 + col*24 + b
        const float x = pts[3 * j + 0], y = pts[3 * j + 1], z = pts[3 * j + 2];
        const _Float16 bhx = (_Float16)x, bhy = (_Float16)y, bhz = (_Float16)z;
        const _Float16 blx = (_Float16)(x - (float)bhx);
        const _Float16 bly = (_Float16)(y - (float)bhy);
        const _Float16 blz = (_Float16)(z - (float)bhz);
        const float q = 0.5f * fmaf(z, z, fmaf(y, y, x * x));
        const _Float16 qh = (_Float16)q;
        const _Float16 ql = (_Float16)(q - (float)qh);
        half8 s0;
        s0[0] = -bhx; s0[1] = -bhy; s0[2] = -bhz;
        s0[3] = -bhx; s0[4] = -bhy; s0[5] = -bhz;
        s0[6] = -blx; s0[7] = -bly;
        half8 s1 = (_Float16)0;
        s1[0] = -blz; s1[1] = qh; s1[2] = ql;
        *(half8*)&sB[(b * 64 + col) * 8]      = s0;   // h=0 lanes
        *(half8*)&sB[(b * 64 + 32 + col) * 8] = s1;   // h=1 lanes
    }

    // own-i q (thread t owns i = iblk + t for the reduce/store phase)
    float qi_t;
    {
        const float x = pts[3 * (iblk + t) + 0];
        const float y = pts[3 * (iblk + t) + 1];
        const float z = pts[3 * (iblk + t) + 2];
        qi_t = 0.5f * fmaf(z, z, fmaf(y, y, x * x));
    }

    // ---- A fragments: wave w owns i-tiles 2w, 2w+1 (32 i's each) ----
    const int lane = t & 63;
    const int w    = t >> 6;
    const int m    = lane & 31;    // A row / D col == cell lane
    const int h    = lane >> 5;    // k-half

    half8  afr[2];
    f32x16 mn[2];
    #pragma unroll
    for (int tau = 0; tau < 2; ++tau) {
        const int i = iblk + (2 * w + tau) * 32 + m;
        const float x = pts[3 * i + 0], y = pts[3 * i + 1], z = pts[3 * i + 2];
        const _Float16 ahx = (_Float16)x, ahy = (_Float16)y, ahz = (_Float16)z;
        const _Float16 alx = (_Float16)(x - (float)ahx);
        const _Float16 aly = (_Float16)(y - (float)ahy);
        const _Float16 alz = (_Float16)(z - (float)alz * 0.0f);  // (no-op)
        half8 a = (_Float16)0;
        if (h == 0) {        // k0-7: ah(xyz), al(xyz), ah(x,y)
            a[0] = ahx; a[1] = ahy; a[2] = ahz;
            a[3] = alx; a[4] = aly; a[5] = (_Float16)(z - (float)ahz);
            a[6] = ahx; a[7] = ahy;
        } else {             // k8-15: ah_z, 1, 1, zeros
            a[0] = ahz; a[1] = (_Float16)1.0f; a[2] = (_Float16)1.0f;
        }
        afr[tau] = a;
        mn[tau] = INFINITY;
        (void)aly; (void)alz;
    }
    __syncthreads();

    if (MODE == 0) {
        const f32x16 zero16 = 0.0f;
        #pragma unroll 2
        for (int b = 0; b < CELLJ; b += 2) {
            const half8 bf0 = *(const half8*)&sB[(b * 64 + lane) * 8];
            const half8 bf1 = *(const half8*)&sB[((b + 1) * 64 + lane) * 8];
            #pragma unroll
            for (int tau = 0; tau < 2; ++tau) {
                const f32x16 d0 = __builtin_amdgcn_mfma_f32_32x32x16_f16(
                    afr[tau], bf0, zero16, 0, 0, 0);
                const f32x16 d1 = __builtin_amdgcn_mfma_f32_32x32x16_f16(
                    afr[tau], bf1, zero16, 0, 0, 0);
                #pragma unroll
                for (int r = 0; r < 16; ++r)
                    mn[tau][r] = fminf(fminf(d0[r], d1[r]), mn[tau][r]);
            }
        }
    } else {
        // ABLATED: keep the 24 ds_read_b128 (forced live), drop MFMA+min
        #pragma unroll 2
        for (int b = 0; b < CELLJ; b += 2) {
            const half8 bf0 = *(const half8*)&sB[(b * 64 + lane) * 8];
            const half8 bf1 = *(const half8*)&sB[((b + 1) * 64 + lane) * 8];
            asm volatile("" :: "v"((float)bf0[0]));
            asm volatile("" :: "v"((float)bf1[0]));
        }
        asm volatile("" :: "v"((float)afr[0][0]), "v"((float)afr[1][0]));
    }
    __syncthreads();   // done with sB; reuse as transpose buffer

    // ---- transpose through LDS: sT[cell][i_loc], stride TSTR ----
    #pragma unroll
    for (int tau = 0; tau < 2; ++tau) {
        #pragma unroll
        for (int gp = 0; gp < 4; ++gp) {
            const float4 v = make_float4(mn[tau][4 * gp + 0],
                                         mn[tau][4 * gp + 1],
                                         mn[tau][4 * gp + 2],
                                         mn[tau][4 * gp + 3]);
            *(float4*)&sT[m * TSTR + (2 * w + tau) * 32 + 4 * h + 8 * gp] = v;
        }
    }
    __syncthreads();

    // ---- per-i reduce: 32 cells -> top-4 packed, ONE float4 store ----
    float t0 = INFINITY, t1 = INFINITY, t2 = INFINITY, t3 = INFINITY;
    #pragma unroll 8
    for (int c = 0; c < 32; ++c) {
        const float v = sT[c * TSTR + t] + qi_t;
        const unsigned cid = (unsigned)(g * 32 + c);
        const float pv = __uint_as_float((__float_as_uint(v) & ~CMASK) | cid);
        ins4(pv, t0, t1, t2, t3);
    }
    ws4[(size_t)g * N_PTS + (iblk + t)] = make_float4(t0, t1, t2, t3);
}

// 768 blocks x 256 threads: block owns 16 i's, 16 workers per i.
__global__ __launch_bounds__(256) void knn_finalize(
    const float4* __restrict__ ws4, const float* __restrict__ pts,
    float* __restrict__ out)
{
    __shared__ float sS[16];
    const int t    = threadIdx.x;
    const int lane = t & 63;
    const int w    = t >> 6;             // wave 0..3
    const int bid  = blockIdx.x;         // 0..767
    const int il2  = lane & 3;           // i-slot within wave
    const int w2   = lane >> 2;          // worker 0..15
    const int i    = bid * 16 + w * 4 + il2;

    // phase 1: worker w2 loads chunk w2's top-4 for i (one float4)
    float c0 = INFINITY, c1 = INFINITY, c2 = INFINITY, c3 = INFINITY;
    {
        const float4 v = ws4[(size_t)w2 * N_PTS + i];
        ins4(v.x, c0, c1, c2, c3);
        ins4(v.y, c0, c1, c2, c3);
        ins4(v.z, c0, c1, c2, c3);
        ins4(v.w, c0, c1, c2, c3);
    }

    // phase 2: butterfly merge across the worker dim (lane bits 2-5)
    #pragma unroll
    for (int mask = 4; mask < 64; mask <<= 1) {
        const float p0 = __shfl_xor(c0, mask);
        const float p1 = __shfl_xor(c1, mask);
        const float p2 = __shfl_xor(c2, mask);
        const float p3 = __shfl_xor(c3, mask);
        ins4(p0, c0, c1, c2, c3);
        ins4(p1, c0, c1, c2, c3);
        ins4(p2, c0, c1, c2, c3);
        ins4(p3, c0, c1, c2, c3);
    }
    // all 16 workers of i-group il2 now hold the global top-4 cells for i

    const float px = pts[3 * i + 0];
    const float py = pts[3 * i + 1];
    const float pz = pts[3 * i + 2];

    // phase 3: exact diff-form rescan. 96 candidates = 4 cells x 24 j.
    // worker w2: cell q = w2>>2, j-offsets (w2&3) + 4k, k<6.
    float b0 = INFINITY, b1 = INFINITY, b2 = INFINITY, b3 = INFINITY;
    {
        const int q = w2 >> 2;
        const float cv_lo = (q & 2) ? c2 : c0;
        const float cv_hi = (q & 2) ? c3 : c1;
        const float cv    = (q & 1) ? cv_hi : cv_lo;
        const int   cid   = (int)(__float_as_uint(cv) & CMASK);
        const int   jb    = (cid >> 5) * CHUNK + (cid & 31) * CELLJ + (w2 & 3);
        #pragma unroll
        for (int k = 0; k < 6; ++k) {
            const int j = jb + 4 * k;
            const float dx = px - pts[3 * j + 0];
            const float dy = py - pts[3 * j + 1];
            const float dz = pz - pts[3 * j + 2];
            const float d2 = fmaf(dz, dz, fmaf(dy, dy, dx * dx));
            ins4(d2, b0, b1, b2, b3);        // j==i gives exactly 0
        }
    }

    // phase 4: butterfly merge of the rescan top-4s
    #pragma unroll
    for (int mask = 4; mask < 64; mask <<= 1) {
        const float p0 = __shfl_xor(b0, mask);
        const float p1 = __shfl_xor(b1, mask);
        const float p2 = __shfl_xor(b2, mask);
        const float p3 = __shfl_xor(b3, mask);
        ins4(p0, b0, b1, b2, b3);
        ins4(p1, b0, b1, b2, b3);
        ins4(p2, b0, b1, b2, b3);
        ins4(p3, b0, b1, b2, b3);
    }

    // b0 == 0 is the self pair; b1..b3 are the true 3-NN squared distances
    if (w2 == 0) {
        const float d0 = sqrtf(b1);
        const float d1 = sqrtf(b2);
        const float d2 = sqrtf(b3);
        float mean = fmaxf((d0 + d1 + d2) * (1.0f / 3.0f), 1e-5f);
        const float s = 0.001f * mean;
        sS[w * 4 + il2] = s * s;
    }
    __syncthreads();

    // coalesced s^2 * I store: 144 floats for this block's 16 i's
    for (int k = t; k < 144; k += 256) {
        const int i3 = k / 9, r = k % 9;
        const float v = (r == 0 || r == 4 || r == 8) ? sS[i3] : 0.0f;
        out[(size_t)(bid * 16 + i3) * 9 + r] = v;
    }
}

extern "C" void kernel_launch(void* const* d_in, const int* in_sizes, int n_in,
                              void* d_out, int out_size, void* d_ws, size_t ws_size,
                              hipStream_t stream) {
    const float* pts = (const float*)d_in[0];   // (N, 3) float32
    // d_in[1] = quaternions: algebraically irrelevant (cov = s^2 * I)
    float4* ws4 = (float4*)d_ws;                // 16 * 12288 * 16B = 3.1 MB
    float*  out = (float*)d_out;                // (N, 3, 3) float32

    cellmin_k<0><<<dim3(NIB, NCH), dim3(256), 0, stream>>>(pts, ws4);
    knn_finalize<<<dim3(N_PTS / 16), dim3(256), 0, stream>>>(ws4, pts, out);

    // R20 ABLATION PROBES (write unused ws regions; timing payload only):
    float4* sh1 = (float4*)((char*)d_ws + (64u << 20));
    float4* sh2 = (float4*)((char*)d_ws + (128u << 20));
    cellmin_k<0><<<dim3(NIB, NCH), dim3(256), 0, stream>>>(pts, sh1);
    cellmin_k<1><<<dim3(NIB, NCH), dim3(256), 0, stream>>>(pts, sh2);
}

// Round 10
// 66.884 us; speedup vs baseline: 1.2368x; 1.2368x over previous
//
#include <hip/hip_runtime.h>
#include <math.h>

// Gaussians covariance, MI355X. cov = s^2 * I exactly (isotropic scales,
// R orthogonal) -> problem is the exact 3-NN search over N^2 pairs.
//
// R21 (BANK ROUND: R20 minus the two shadow ablation launches):
//  - R20 ablation read-out: cellmin 7.8us = 2.3 compute core (MFMA+min,
//    == issue-bound model at 3 waves/SIMD) + 5.5 everything-else
//    (staging/LDS/transpose/reduce ~2.7 modeled + ~2.5 barrier/ramp slop).
//  - Full ledger (measured): fill 40.2 | harness resets ~13.7 | cellmin
//    7.8 | finalize 2.0 | 2 gaps 3.1 (1.55 each, R19 probe). Harness-fixed
//    ~53.9us; controllable ~12.9, mostly at structural floor.
//  - Rejected after audit: fan-in fused finalize (XCD L2 non-coherence
//    demands AGENT-scope release stores / wbl2 fences + counter memset
//    dispatch -> net ~+1us at real correctness risk, G16); IBLK=384
//    repack (+0.3-0.5us, geometry reroll risk); sT-flip/swizzle (R12).
//  - Kernels BYTE-IDENTICAL to R20's verified MODE-0 path
//    (= R17 + b128 transpose writes, TSTR=260).
// NOTE: ~54us of the timed window is harness-fixed (fill + resets).

#define N_PTS 12288
#define CHUNK 768               // j's per chunk
#define NCH   (N_PTS / CHUNK)   // 16 chunks
#define CELLJ 24                // consecutive j's per cell; 32 cells/chunk
#define IBLK  256               // i's per pass-A block
#define NIB   (N_PTS / IBLK)    // 48
#define TSTR  260               // LDS transpose stride (dwords), 16B-aligned
#define CMASK 1023u             // 10-bit cell id (512 cells used)

typedef _Float16 half8  __attribute__((ext_vector_type(8)));
typedef float    f32x16 __attribute__((ext_vector_type(16)));

__device__ __forceinline__ void ins4(float d, float& a0, float& a1,
                                     float& a2, float& a3) {
    // insert d into sorted a0<=a1<=a2<=a3, keep 4 smallest (4 VALU)
    const float n0 = fminf(a0, d);
    const float n1 = __builtin_amdgcn_fmed3f(a0, a1, d);
    const float n2 = __builtin_amdgcn_fmed3f(a1, a2, d);
    const float n3 = __builtin_amdgcn_fmed3f(a2, a3, d);
    a0 = n0; a1 = n1; a2 = n2; a3 = n3;
}

__global__ __launch_bounds__(256, 3) void cellmin_mfma(
    const float* __restrict__ pts, float4* __restrict__ ws4)
{
    // union: sB (24 b-iters x 64 lane-slots x 8 halves = 24KB) during MFMA,
    // then sT (32 cells x 256 i, stride TSTR = 33.3KB) for the transpose
    __shared__ __align__(16) unsigned char shmem[32 * TSTR * 4];
    _Float16* sB = (_Float16*)shmem;
    float*    sT = (float*)shmem;

    const int t    = threadIdx.x;
    const int iblk = blockIdx.x * IBLK;
    const int g    = blockIdx.y;           // chunk 0..15

    // ---- stage B fragments: COALESCED (consecutive t -> consecutive j) ----
    // cell col holds j = g*768 + col*24 + b, col = idx/24, b = idx%24.
    // Slot layout: slot = b*64 + col (s0), +32 (s1)  [R11 linear layout]
    // K slots (h=0): k0-2 = -bh(xyz) (vs ah), k3-5 = -bh(xyz) (vs al),
    //                k6-7 = -bl(x,y) (vs ah)
    //        (h=1): k8 = -bl_z (vs ah_z), k9 = qh, k10 = ql (vs 1), rest 0
    #pragma unroll
    for (int it = 0; it < 3; ++it) {
        const int idx = t + it * 256;
        const int col = idx / CELLJ, b = idx % CELLJ;
        const int j = g * CHUNK + idx;       // == g*768 + col*24 + b
        const float x = pts[3 * j + 0], y = pts[3 * j + 1], z = pts[3 * j + 2];
        const _Float16 bhx = (_Float16)x, bhy = (_Float16)y, bhz = (_Float16)z;
        const _Float16 blx = (_Float16)(x - (float)bhx);
        const _Float16 bly = (_Float16)(y - (float)bhy);
        const _Float16 blz = (_Float16)(z - (float)bhz);
        const float q = 0.5f * fmaf(z, z, fmaf(y, y, x * x));
        const _Float16 qh = (_Float16)q;
        const _Float16 ql = (_Float16)(q - (float)qh);
        half8 s0;
        s0[0] = -bhx; s0[1] = -bhy; s0[2] = -bhz;
        s0[3] = -bhx; s0[4] = -bhy; s0[5] = -bhz;
        s0[6] = -blx; s0[7] = -bly;
        half8 s1 = (_Float16)0;
        s1[0] = -blz; s1[1] = qh; s1[2] = ql;
        *(half8*)&sB[(b * 64 + col) * 8]      = s0;   // h=0 lanes
        *(half8*)&sB[(b * 64 + 32 + col) * 8] = s1;   // h=1 lanes
    }

    // own-i q (thread t owns i = iblk + t for the reduce/store phase)
    float qi_t;
    {
        const float x = pts[3 * (iblk + t) + 0];
        const float y = pts[3 * (iblk + t) + 1];
        const float z = pts[3 * (iblk + t) + 2];
        qi_t = 0.5f * fmaf(z, z, fmaf(y, y, x * x));
    }

    // ---- A fragments: wave w owns i-tiles 2w, 2w+1 (32 i's each) ----
    const int lane = t & 63;
    const int w    = t >> 6;
    const int m    = lane & 31;    // A row / D col == cell lane
    const int h    = lane >> 5;    // k-half

    half8  afr[2];
    f32x16 mn[2];
    #pragma unroll
    for (int tau = 0; tau < 2; ++tau) {
        const int i = iblk + (2 * w + tau) * 32 + m;
        const float x = pts[3 * i + 0], y = pts[3 * i + 1], z = pts[3 * i + 2];
        const _Float16 ahx = (_Float16)x, ahy = (_Float16)y, ahz = (_Float16)z;
        const _Float16 alx = (_Float16)(x - (float)ahx);
        const _Float16 aly = (_Float16)(y - (float)ahy);
        const _Float16 alz = (_Float16)(z - (float)ahz);
        half8 a = (_Float16)0;
        if (h == 0) {        // k0-7: ah(xyz), al(xyz), ah(x,y)
            a[0] = ahx; a[1] = ahy; a[2] = ahz;
            a[3] = alx; a[4] = aly; a[5] = alz;
            a[6] = ahx; a[7] = ahy;
        } else {             // k8-15: ah_z, 1, 1, zeros
            a[0] = ahz; a[1] = (_Float16)1.0f; a[2] = (_Float16)1.0f;
        }
        afr[tau] = a;
        mn[tau] = INFINITY;
    }
    __syncthreads();

    const f32x16 zero16 = 0.0f;
    #pragma unroll 2
    for (int b = 0; b < CELLJ; b += 2) {
        const half8 bf0 = *(const half8*)&sB[(b * 64 + lane) * 8];
        const half8 bf1 = *(const half8*)&sB[((b + 1) * 64 + lane) * 8];
        #pragma unroll
        for (int tau = 0; tau < 2; ++tau) {
            const f32x16 d0 = __builtin_amdgcn_mfma_f32_32x32x16_f16(
                afr[tau], bf0, zero16, 0, 0, 0);
            const f32x16 d1 = __builtin_amdgcn_mfma_f32_32x32x16_f16(
                afr[tau], bf1, zero16, 0, 0, 0);
            #pragma unroll
            for (int r = 0; r < 16; ++r)
                mn[tau][r] = fminf(fminf(d0[r], d1[r]), mn[tau][r]);
        }
    }
    __syncthreads();   // done with sB; reuse as transpose buffer

    // ---- transpose through LDS: sT[cell][i_loc], stride TSTR ----
    // rows for r=4g+e are e+8g+4h: 4 consecutive dwords per g -> b128.
    // lane m base m*260 = 0 mod 4 -> 16B aligned.
    #pragma unroll
    for (int tau = 0; tau < 2; ++tau) {
        #pragma unroll
        for (int gp = 0; gp < 4; ++gp) {
            const float4 v = make_float4(mn[tau][4 * gp + 0],
                                         mn[tau][4 * gp + 1],
                                         mn[tau][4 * gp + 2],
                                         mn[tau][4 * gp + 3]);
            *(float4*)&sT[m * TSTR + (2 * w + tau) * 32 + 4 * h + 8 * gp] = v;
        }
    }
    __syncthreads();

    // ---- per-i reduce: 32 cells -> top-4 packed, ONE float4 store ----
    float t0 = INFINITY, t1 = INFINITY, t2 = INFINITY, t3 = INFINITY;
    #pragma unroll 8
    for (int c = 0; c < 32; ++c) {
        const float v = sT[c * TSTR + t] + qi_t;
        const unsigned cid = (unsigned)(g * 32 + c);
        const float pv = __uint_as_float((__float_as_uint(v) & ~CMASK) | cid);
        ins4(pv, t0, t1, t2, t3);
    }
    ws4[(size_t)g * N_PTS + (iblk + t)] = make_float4(t0, t1, t2, t3);
}

// 768 blocks x 256 threads: block owns 16 i's, 16 workers per i.
__global__ __launch_bounds__(256) void knn_finalize(
    const float4* __restrict__ ws4, const float* __restrict__ pts,
    float* __restrict__ out)
{
    __shared__ float sS[16];
    const int t    = threadIdx.x;
    const int lane = t & 63;
    const int w    = t >> 6;             // wave 0..3
    const int bid  = blockIdx.x;         // 0..767
    const int il2  = lane & 3;           // i-slot within wave
    const int w2   = lane >> 2;          // worker 0..15
    const int i    = bid * 16 + w * 4 + il2;

    // phase 1: worker w2 loads chunk w2's top-4 for i (one float4)
    float c0 = INFINITY, c1 = INFINITY, c2 = INFINITY, c3 = INFINITY;
    {
        const float4 v = ws4[(size_t)w2 * N_PTS + i];
        ins4(v.x, c0, c1, c2, c3);
        ins4(v.y, c0, c1, c2, c3);
        ins4(v.z, c0, c1, c2, c3);
        ins4(v.w, c0, c1, c2, c3);
    }

    // phase 2: butterfly merge across the worker dim (lane bits 2-5)
    #pragma unroll
    for (int mask = 4; mask < 64; mask <<= 1) {
        const float p0 = __shfl_xor(c0, mask);
        const float p1 = __shfl_xor(c1, mask);
        const float p2 = __shfl_xor(c2, mask);
        const float p3 = __shfl_xor(c3, mask);
        ins4(p0, c0, c1, c2, c3);
        ins4(p1, c0, c1, c2, c3);
        ins4(p2, c0, c1, c2, c3);
        ins4(p3, c0, c1, c2, c3);
    }
    // all 16 workers of i-group il2 now hold the global top-4 cells for i

    const float px = pts[3 * i + 0];
    const float py = pts[3 * i + 1];
    const float pz = pts[3 * i + 2];

    // phase 3: exact diff-form rescan. 96 candidates = 4 cells x 24 j.
    // worker w2: cell q = w2>>2, j-offsets (w2&3) + 4k, k<6.
    // branchless cell select (no runtime-indexed array -> no scratch):
    float b0 = INFINITY, b1 = INFINITY, b2 = INFINITY, b3 = INFINITY;
    {
        const int q = w2 >> 2;
        const float cv_lo = (q & 2) ? c2 : c0;
        const float cv_hi = (q & 2) ? c3 : c1;
        const float cv    = (q & 1) ? cv_hi : cv_lo;
        const int   cid   = (int)(__float_as_uint(cv) & CMASK);
        const int   jb    = (cid >> 5) * CHUNK + (cid & 31) * CELLJ + (w2 & 3);
        #pragma unroll
        for (int k = 0; k < 6; ++k) {
            const int j = jb + 4 * k;
            const float dx = px - pts[3 * j + 0];
            const float dy = py - pts[3 * j + 1];
            const float dz = pz - pts[3 * j + 2];
            const float d2 = fmaf(dz, dz, fmaf(dy, dy, dx * dx));
            ins4(d2, b0, b1, b2, b3);        // j==i gives exactly 0
        }
    }

    // phase 4: butterfly merge of the rescan top-4s
    #pragma unroll
    for (int mask = 4; mask < 64; mask <<= 1) {
        const float p0 = __shfl_xor(b0, mask);
        const float p1 = __shfl_xor(b1, mask);
        const float p2 = __shfl_xor(b2, mask);
        const float p3 = __shfl_xor(b3, mask);
        ins4(p0, b0, b1, b2, b3);
        ins4(p1, b0, b1, b2, b3);
        ins4(p2, b0, b1, b2, b3);
        ins4(p3, b0, b1, b2, b3);
    }

    // b0 == 0 is the self pair; b1..b3 are the true 3-NN squared distances
    if (w2 == 0) {
        const float d0 = sqrtf(b1);
        const float d1 = sqrtf(b2);
        const float d2 = sqrtf(b3);
        float mean = fmaxf((d0 + d1 + d2) * (1.0f / 3.0f), 1e-5f);
        const float s = 0.001f * mean;
        sS[w * 4 + il2] = s * s;
    }
    __syncthreads();

    // coalesced s^2 * I store: 144 floats for this block's 16 i's
    for (int k = t; k < 144; k += 256) {
        const int i3 = k / 9, r = k % 9;
        const float v = (r == 0 || r == 4 || r == 8) ? sS[i3] : 0.0f;
        out[(size_t)(bid * 16 + i3) * 9 + r] = v;
    }
}

extern "C" void kernel_launch(void* const* d_in, const int* in_sizes, int n_in,
                              void* d_out, int out_size, void* d_ws, size_t ws_size,
                              hipStream_t stream) {
    const float* pts = (const float*)d_in[0];   // (N, 3) float32
    // d_in[1] = quaternions: algebraically irrelevant (cov = s^2 * I)
    float4* ws4 = (float4*)d_ws;                // 16 * 12288 * 16B = 3.1 MB
    float*  out = (float*)d_out;                // (N, 3, 3) float32

    cellmin_mfma<<<dim3(NIB, NCH), dim3(256), 0, stream>>>(pts, ws4);
    knn_finalize<<<dim3(N_PTS / 16), dim3(256), 0, stream>>>(ws4, pts, out);
}